// Round 17
// baseline (361.459 us; speedup 1.0000x reference)
//
#include <hip/hip_runtime.h>
#include <cstdint>
#include <cstddef>
#include <math.h>

#define N_NODES 100000
#define N_EDGES 1600000
#define DIM 128
#define DOUT 40
#define BN_EPS 1e-5f

// bucketed CSR build
#define NB 500          // buckets
#define NPB 200         // nodes per bucket (500*200 = 100000 exactly)
#define BCAP 4096       // bucket capacity (mean 3200 -> ~16 sigma headroom)
#define BKT_BLOCKS 400
#define EPB (N_EDGES / BKT_BLOCKS)   // 4000

typedef __attribute__((ext_vector_type(8))) short bf16x8;
typedef __attribute__((ext_vector_type(4))) float f32x4;

__device__ __forceinline__ float bf2f(uint u16shifted) {
    union { uint i; float f; } c; c.i = u16shifted; return c.f;
}
__device__ __forceinline__ ushort f2bf(float f) {
    union { float f; uint i; } c; c.f = f;
    uint i = c.i;
    uint lsb = (i >> 16) & 1u;
    i += 0x7FFFu + lsb;
    return (ushort)(i >> 16);
}
__device__ __forceinline__ uint bnpack(uint u, float s0, float h0, float s1, float h1) {
    float lo = fmaxf(bf2f(u << 16) * s0 + h0, 0.f);
    float hi = fmaxf(bf2f(u & 0xFFFF0000u) * s1 + h1, 0.f);
    return (uint)f2bf(lo) | ((uint)f2bf(hi) << 16);
}

// Wcat FRAGMENT layout: for col-fragment fc (=col>>4) and K-step ks (=k>>5),
// fragment base = (fc*8+ks)*512 ushorts; within, lane l holds elems l*8..l*8+7
__device__ __forceinline__ void wcat_body(const float* __restrict__ W,
                                          const float* __restrict__ R,
                                          ushort* __restrict__ out, int NW, int blk) {
    int idx = blk * 256 + threadIdx.x;      // idx over Ncols*256
    int n = idx >> 8, k = idx & 255;
    float v = 0.f;
    if (n < NW) v = (k < 128) ? W[k * NW + n] : R[(k - 128) * NW + n];
    int fc = n >> 4, l15 = n & 15;
    int ks = k >> 5, lhi = (k & 31) >> 3, j = k & 7;
    out[(fc * 8 + ks) * 512 + (lhi * 16 + l15) * 8 + j] = f2bf(v);
}

// ---------------- fused prep: bucket (0..399, int4-vectorized) + cvt + wcat x3 -------------
__global__ __launch_bounds__(256) void k_prep(const float* __restrict__ x,
                                              ushort* __restrict__ Xb,
                                              const float* __restrict__ w1, const float* __restrict__ r1, ushort* __restrict__ Wc1,
                                              const float* __restrict__ w2, const float* __restrict__ r2, ushort* __restrict__ Wc2,
                                              const float* __restrict__ w3, const float* __restrict__ r3, ushort* __restrict__ Wc3,
                                              const int* __restrict__ ei,
                                              uint* __restrict__ bucketbuf,
                                              int* __restrict__ gcnt) {
    int b = blockIdx.x;
    int tid = threadIdx.x;
    if (b < BKT_BLOCKS) {
        // bucket pass: partition edges into dst-buckets; int4 loads = 4 edges/thread/iter
        __shared__ int hist[NB];
        __shared__ int base_[NB];
        for (int i = tid; i < NB; i += 256) hist[i] = 0;
        __syncthreads();
        int e0 = b * EPB, e1 = e0 + EPB;
        for (int e = e0 + tid * 4; e < e1; e += 1024) {
            int4 d4 = *reinterpret_cast<const int4*>(ei + N_EDGES + e);
            atomicAdd(&hist[d4.x / NPB], 1);
            atomicAdd(&hist[d4.y / NPB], 1);
            atomicAdd(&hist[d4.z / NPB], 1);
            atomicAdd(&hist[d4.w / NPB], 1);
        }
        __syncthreads();
        for (int i = tid; i < NB; i += 256) base_[i] = atomicAdd(&gcnt[i], hist[i]);
        __syncthreads();
        for (int i = tid; i < NB; i += 256) hist[i] = 0;
        __syncthreads();
        for (int e = e0 + tid * 4; e < e1; e += 1024) {
            int4 d4 = *reinterpret_cast<const int4*>(ei + N_EDGES + e);
            int4 s4 = *reinterpret_cast<const int4*>(ei + e);
            int bk0 = d4.x / NPB, bk1 = d4.y / NPB, bk2 = d4.z / NPB, bk3 = d4.w / NPB;
            int p0 = base_[bk0] + atomicAdd(&hist[bk0], 1);
            int p1 = base_[bk1] + atomicAdd(&hist[bk1], 1);
            int p2 = base_[bk2] + atomicAdd(&hist[bk2], 1);
            int p3 = base_[bk3] + atomicAdd(&hist[bk3], 1);
            if (p0 < BCAP) bucketbuf[(size_t)bk0 * BCAP + p0] = ((uint)(d4.x - bk0 * NPB) << 17) | (uint)s4.x;
            if (p1 < BCAP) bucketbuf[(size_t)bk1 * BCAP + p1] = ((uint)(d4.y - bk1 * NPB) << 17) | (uint)s4.y;
            if (p2 < BCAP) bucketbuf[(size_t)bk2 * BCAP + p2] = ((uint)(d4.z - bk2 * NPB) << 17) | (uint)s4.z;
            if (p3 < BCAP) bucketbuf[(size_t)bk3 * BCAP + p3] = ((uint)(d4.w - bk3 * NPB) << 17) | (uint)s4.w;
        }
    } else if (b < BKT_BLOCKS + 2048) {
        int n4 = N_NODES * DIM / 4;
        int i = (b - BKT_BLOCKS) * 256 + tid;
        int stride = 2048 * 256;
        for (; i < n4; i += stride) {
            float4 v = reinterpret_cast<const float4*>(x)[i];
            ushort4 o;
            o.x = f2bf(v.x); o.y = f2bf(v.y); o.z = f2bf(v.z); o.w = f2bf(v.w);
            reinterpret_cast<ushort4*>(Xb)[i] = o;
        }
    } else if (b < BKT_BLOCKS + 2048 + 128) {
        wcat_body(w1, r1, Wc1, 128, b - (BKT_BLOCKS + 2048));
    } else if (b < BKT_BLOCKS + 2048 + 256) {
        wcat_body(w2, r2, Wc2, 128, b - (BKT_BLOCKS + 2048 + 128));
    } else {
        wcat_body(w3, r3, Wc3, DOUT, b - (BKT_BLOCKS + 2048 + 256));
    }
}

// ---------------- CSR pass B: per-bucket CSR entirely in LDS (self-computed base) ----------
__global__ __launch_bounds__(256) void k_csr_build(const int* __restrict__ ei,
                                                   const uint* __restrict__ bucketbuf,
                                                   const int* __restrict__ gcnt,
                                                   int* __restrict__ rowstart,
                                                   int* __restrict__ csr) {
    __shared__ int cnts[NPB + 1];
    __shared__ int lcur[NPB];
    __shared__ int csr_l[BCAP];
    __shared__ int baseS;
    int b = blockIdx.x, tid = threadIdx.x;
    int cnt = gcnt[b];
    int lo = b * NPB;
    if (tid == 0) baseS = 0;
    for (int i = tid; i < NPB; i += 256) cnts[i] = 0;
    __syncthreads();
    int part = 0;
    for (int i = tid; i < b; i += 256) part += gcnt[i];
    if (part) atomicAdd(&baseS, part);
    bool fits = (cnt <= BCAP);
    if (fits) {
        for (int i = tid; i < cnt; i += 256)
            atomicAdd(&cnts[bucketbuf[(size_t)b * BCAP + i] >> 17], 1);
    } else {  // overflow fallback (statistically never)
        for (int e = tid; e < N_EDGES; e += 256) {
            int d = ei[N_EDGES + e];
            if (d >= lo && d < lo + NPB) atomicAdd(&cnts[d - lo], 1);
        }
    }
    __syncthreads();
    int base = baseS;
    if (tid == 0) {
        int run = 0;
        for (int i = 0; i < NPB; i++) { int c = cnts[i]; cnts[i] = run; run += c; }
        cnts[NPB] = run;
    }
    __syncthreads();
    for (int i = tid; i < NPB; i += 256) rowstart[lo + i] = base + cnts[i];
    if (b == NB - 1 && tid == 0) rowstart[N_NODES] = N_EDGES;
    for (int i = tid; i < NPB; i += 256) lcur[i] = 0;
    __syncthreads();
    if (fits) {
        for (int i = tid; i < cnt; i += 256) {
            uint p = bucketbuf[(size_t)b * BCAP + i];
            int dl = p >> 17;
            int pos = cnts[dl] + atomicAdd(&lcur[dl], 1);
            csr_l[pos] = (int)(p & 0x1FFFFu);
        }
        __syncthreads();
        for (int i = tid; i < cnt; i += 256) csr[base + i] = csr_l[i];
    } else {
        for (int e = tid; e < N_EDGES; e += 256) {
            int d = ei[N_EDGES + e];
            if (d >= lo && d < lo + NPB) {
                int dl = d - lo;
                int pos = cnts[dl] + atomicAdd(&lcur[dl], 1);
                csr[base + pos] = ei[e];
            }
        }
    }
}

// ---------------- BN+ReLU materialization, in-place, vectorized ----------------
__global__ __launch_bounds__(256) void k_bnrelu(ushort* __restrict__ H,
                                                const float* __restrict__ stats,
                                                const float* __restrict__ g,
                                                const float* __restrict__ be) {
    __shared__ float scS[128], shS[128];
    int tid = threadIdx.x;
    if (tid < 128) {
        float mu = stats[tid] * (1.0f / N_NODES);
        float var = stats[128 + tid] * (1.0f / N_NODES) - mu * mu;
        float sc = g[tid] * rsqrtf(var + BN_EPS);
        scS[tid] = sc;
        shS[tid] = be[tid] - mu * sc;
    }
    __syncthreads();
    uint4* H4 = reinterpret_cast<uint4*>(H);
    const int total = N_NODES * 16;   // uint4 per row = 16
    for (int i = blockIdx.x * 256 + tid; i < total; i += gridDim.x * 256) {
        uint4 u = H4[i];
        int c0 = (i & 15) * 8;
        u.x = bnpack(u.x, scS[c0 + 0], shS[c0 + 0], scS[c0 + 1], shS[c0 + 1]);
        u.y = bnpack(u.y, scS[c0 + 2], shS[c0 + 2], scS[c0 + 3], shS[c0 + 3]);
        u.z = bnpack(u.z, scS[c0 + 4], shS[c0 + 4], scS[c0 + 5], shS[c0 + 5]);
        u.w = bnpack(u.w, scS[c0 + 6], shS[c0 + 6], scS[c0 + 7], shS[c0 + 7]);
        H4[i] = u;
    }
}

// ---------------- mean aggregation, bf16, 16 gathers in flight (pure unpack+add) -----------
// one wave per node; lane = slot(0..3) x colgroup(0..15); each lane loads uint4 = 8 bf16 cols
// main loop: 16 edges (4 per slot) with 4 independent csr loads + 4 independent gathers
__global__ __launch_bounds__(256) void k_agg_bf(const ushort* __restrict__ cur,
                                                const int* __restrict__ rowstart,
                                                const int* __restrict__ csr,
                                                ushort* __restrict__ out) {
    int wid = (blockIdx.x * blockDim.x + threadIdx.x) >> 6;
    int lane = threadIdx.x & 63;
    if (wid >= N_NODES) return;
    int beg = rowstart[wid];
    int end = rowstart[wid + 1];
    int slot = lane >> 4;   // which edge within a group of 4
    int cg = lane & 15;     // column group: cols cg*8 .. cg*8+7
    const uint4* base = reinterpret_cast<const uint4*>(cur);
    float a0 = 0.f, a1 = 0.f, a2 = 0.f, a3 = 0.f, a4 = 0.f, a5 = 0.f, a6 = 0.f, a7 = 0.f;

#define ACCUM(u) do { \
        a0 += bf2f((u).x << 16); a1 += bf2f((u).x & 0xFFFF0000u); \
        a2 += bf2f((u).y << 16); a3 += bf2f((u).y & 0xFFFF0000u); \
        a4 += bf2f((u).z << 16); a5 += bf2f((u).z & 0xFFFF0000u); \
        a6 += bf2f((u).w << 16); a7 += bf2f((u).w & 0xFFFF0000u); \
    } while (0)

    int e = beg + slot;
    // main: 16 edges per wave-iteration (4 per slot), 4 independent chains
    for (; e + 12 < end; e += 16) {
        int s0 = csr[e];
        int s1 = csr[e + 4];
        int s2 = csr[e + 8];
        int s3 = csr[e + 12];
        uint4 u0 = base[(size_t)s0 * 16 + cg];
        uint4 u1 = base[(size_t)s1 * 16 + cg];
        uint4 u2 = base[(size_t)s2 * 16 + cg];
        uint4 u3 = base[(size_t)s3 * 16 + cg];
        ACCUM(u0); ACCUM(u1); ACCUM(u2); ACCUM(u3);
    }
    // tail: 4 edges per iteration
    for (; e < end; e += 4) {
        int s = csr[e];
        uint4 u = base[(size_t)s * 16 + cg];
        ACCUM(u);
    }
#undef ACCUM

#pragma unroll
    for (int off = 16; off < 64; off <<= 1) {
        a0 += __shfl_xor(a0, off, 64); a1 += __shfl_xor(a1, off, 64);
        a2 += __shfl_xor(a2, off, 64); a3 += __shfl_xor(a3, off, 64);
        a4 += __shfl_xor(a4, off, 64); a5 += __shfl_xor(a5, off, 64);
        a6 += __shfl_xor(a6, off, 64); a7 += __shfl_xor(a7, off, 64);
    }
    if (slot == 0) {
        int deg = end - beg;
        float inv = 1.0f / (float)(deg > 1 ? deg : 1);
        uint4 o;
        o.x = (uint)f2bf(a0 * inv) | ((uint)f2bf(a1 * inv) << 16);
        o.y = (uint)f2bf(a2 * inv) | ((uint)f2bf(a3 * inv) << 16);
        o.z = (uint)f2bf(a4 * inv) | ((uint)f2bf(a5 * inv) << 16);
        o.w = (uint)f2bf(a6 * inv) | ((uint)f2bf(a7 * inv) << 16);
        reinterpret_cast<uint4*>(out)[(size_t)wid * 16 + cg] = o;
    }
}

// ---------------- MFMA GEMM v4: pipelined staging (mean LDS -> self regs in flight) -------
// out[M,128] = mean@W + cur@R + b, fused col-stats.
__global__ __launch_bounds__(256, 2) void k_gemm_mfma(const ushort* __restrict__ Am,
                                                      const ushort* __restrict__ Ac,
                                                      const ushort* __restrict__ Wcat, // frag layout
                                                      const float* __restrict__ bias,
                                                      ushort* __restrict__ out,
                                                      float* __restrict__ stats_out,
                                                      int dostats) {
    __shared__ ushort A2[2][128][136];   // 69.6 KB
    __shared__ float lsum[128], lsumsq[128];
    int tid = threadIdx.x;
    int wid = tid >> 6, lane = tid & 63;
    int wr = wid >> 1, wc = wid & 1;
    int l15 = lane & 15, lhi = lane >> 4;
    int row0 = blockIdx.x * 128;

    if (tid < 128) { lsum[tid] = 0.f; lsumsq[tid] = 0.f; }

    // stage mean half into LDS[0]
#pragma unroll
    for (int i = 0; i < 8; ++i) {
        int idx = i * 256 + tid;
        int row = idx >> 4, q = idx & 15;
        int gr = row0 + row;
        uint4 v = {0, 0, 0, 0};
        if (gr < N_NODES)
            v = *reinterpret_cast<const uint4*>(Am + (size_t)gr * 128 + q * 8);
        *reinterpret_cast<uint4*>(&A2[0][row][q * 8]) = v;
    }
    // issue self-half loads into registers (in flight across the first MFMA phase)
    uint4 sreg[8];
#pragma unroll
    for (int i = 0; i < 8; ++i) {
        int idx = i * 256 + tid;
        int row = idx >> 4, q = idx & 15;
        int gr = row0 + row;
        uint4 v = {0, 0, 0, 0};
        if (gr < N_NODES)
            v = *reinterpret_cast<const uint4*>(Ac + (size_t)gr * 128 + q * 8);
        sreg[i] = v;
    }
    __syncthreads();

    f32x4 acc[4][4];
#pragma unroll
    for (int m = 0; m < 4; m++)
#pragma unroll
        for (int n = 0; n < 4; n++) acc[m][n] = (f32x4){0.f, 0.f, 0.f, 0.f};

    // ks 0..3 on mean half (self loads still in flight)
#pragma unroll
    for (int ks = 0; ks < 4; ++ks) {
        int ka = ks * 32 + lhi * 8;
        bf16x8 a[4], b[4];
#pragma unroll
        for (int m = 0; m < 4; m++)
            a[m] = *reinterpret_cast<bf16x8*>(&A2[0][wr * 64 + m * 16 + l15][ka]);
#pragma unroll
        for (int n = 0; n < 4; n++)
            b[n] = *reinterpret_cast<const bf16x8*>(Wcat + ((wc * 4 + n) * 8 + ks) * 512 + lane * 8);
#pragma unroll
        for (int m = 0; m < 4; m++)
#pragma unroll
            for (int n = 0; n < 4; n++)
                acc[m][n] = __builtin_amdgcn_mfma_f32_16x16x32_bf16(a[m], b[n], acc[m][n], 0, 0, 0);
    }
    // write self half to LDS[1]
#pragma unroll
    for (int i = 0; i < 8; ++i) {
        int idx = i * 256 + tid;
        int row = idx >> 4, q = idx & 15;
        *reinterpret_cast<uint4*>(&A2[1][row][q * 8]) = sreg[i];
    }
    __syncthreads();
    // ks 4..7 on self half
#pragma unroll
    for (int ks = 4; ks < 8; ++ks) {
        int ka = (ks - 4) * 32 + lhi * 8;
        bf16x8 a[4], b[4];
#pragma unroll
        for (int m = 0; m < 4; m++)
            a[m] = *reinterpret_cast<bf16x8*>(&A2[1][wr * 64 + m * 16 + l15][ka]);
#pragma unroll
        for (int n = 0; n < 4; n++)
            b[n] = *reinterpret_cast<const bf16x8*>(Wcat + ((wc * 4 + n) * 8 + ks) * 512 + lane * 8);
#pragma unroll
        for (int m = 0; m < 4; m++)
#pragma unroll
            for (int n = 0; n < 4; n++)
                acc[m][n] = __builtin_amdgcn_mfma_f32_16x16x32_bf16(a[m], b[n], acc[m][n], 0, 0, 0);
    }
    // epilogue: + bias, bf16 store, per-column stats partials
    float ps[4] = {0.f, 0.f, 0.f, 0.f}, ps2[4] = {0.f, 0.f, 0.f, 0.f};
#pragma unroll
    for (int m = 0; m < 4; m++) {
        int rbase = row0 + wr * 64 + m * 16 + lhi * 4;
#pragma unroll
        for (int n = 0; n < 4; n++) {
            int col = wc * 64 + n * 16 + l15;
            float bv = bias[col];
#pragma unroll
            for (int j = 0; j < 4; j++) {
                int gr = rbase + j;
                if (gr < N_NODES) {
                    float v = acc[m][n][j] + bv;
                    out[(size_t)gr * 128 + col] = f2bf(v);
                    ps[n] += v;
                    ps2[n] += v * v;
                }
            }
        }
    }
    if (dostats) {
#pragma unroll
        for (int n = 0; n < 4; n++) {
            ps[n] += __shfl_xor(ps[n], 16, 64);
            ps2[n] += __shfl_xor(ps2[n], 16, 64);
            ps[n] += __shfl_xor(ps[n], 32, 64);
            ps2[n] += __shfl_xor(ps2[n], 32, 64);
        }
        if (lhi == 0) {
#pragma unroll
            for (int n = 0; n < 4; n++) {
                int col = wc * 64 + n * 16 + l15;
                atomicAdd(&lsum[col], ps[n]);
                atomicAdd(&lsumsq[col], ps2[n]);
            }
        }
        __syncthreads();
        if (tid < 128) {
            atomicAdd(&stats_out[tid], lsum[tid]);
            atomicAdd(&stats_out[128 + tid], lsumsq[tid]);
        }
    }
}

// ---------------- layer-3 GEMM v4: pipelined staging + frag B + bias + log_softmax --------
__global__ __launch_bounds__(256, 2) void k_gemm40_mfma(const ushort* __restrict__ Am,
                                                        const ushort* __restrict__ Ac,
                                                        const ushort* __restrict__ Wcat, // frag layout [3 fc][8 ks][512]
                                                        const float* __restrict__ bias,  // [40]
                                                        float* __restrict__ out) {
    __shared__ ushort A2[2][128][136];
    int tid = threadIdx.x;
    int w = tid >> 6, lane = tid & 63;
    int l15 = lane & 15, lhi = lane >> 4;
    int row0 = blockIdx.x * 128;

    // stage mean half
#pragma unroll
    for (int i = 0; i < 8; ++i) {
        int idx = i * 256 + tid;
        int row = idx >> 4, q = idx & 15;
        int gr = row0 + row;
        uint4 v = {0, 0, 0, 0};
        if (gr < N_NODES)
            v = *reinterpret_cast<const uint4*>(Am + (size_t)gr * 128 + q * 8);
        *reinterpret_cast<uint4*>(&A2[0][row][q * 8]) = v;
    }
    uint4 sreg[8];
#pragma unroll
    for (int i = 0; i < 8; ++i) {
        int idx = i * 256 + tid;
        int row = idx >> 4, q = idx & 15;
        int gr = row0 + row;
        uint4 v = {0, 0, 0, 0};
        if (gr < N_NODES)
            v = *reinterpret_cast<const uint4*>(Ac + (size_t)gr * 128 + q * 8);
        sreg[i] = v;
    }
    __syncthreads();

    f32x4 acc[2][3];
#pragma unroll
    for (int m = 0; m < 2; m++)
#pragma unroll
        for (int n = 0; n < 3; n++) acc[m][n] = (f32x4){0.f, 0.f, 0.f, 0.f};

#pragma unroll
    for (int ks = 0; ks < 4; ++ks) {
        int ka = ks * 32 + lhi * 8;
        bf16x8 a[2], b[3];
#pragma unroll
        for (int m = 0; m < 2; m++)
            a[m] = *reinterpret_cast<bf16x8*>(&A2[0][w * 32 + m * 16 + l15][ka]);
#pragma unroll
        for (int n = 0; n < 3; n++)
            b[n] = *reinterpret_cast<const bf16x8*>(Wcat + (n * 8 + ks) * 512 + lane * 8);
#pragma unroll
        for (int m = 0; m < 2; m++)
#pragma unroll
            for (int n = 0; n < 3; n++)
                acc[m][n] = __builtin_amdgcn_mfma_f32_16x16x32_bf16(a[m], b[n], acc[m][n], 0, 0, 0);
    }
#pragma unroll
    for (int i = 0; i < 8; ++i) {
        int idx = i * 256 + tid;
        int row = idx >> 4, q = idx & 15;
        *reinterpret_cast<uint4*>(&A2[1][row][q * 8]) = sreg[i];
    }
    __syncthreads();
#pragma unroll
    for (int ks = 4; ks < 8; ++ks) {
        int ka = (ks - 4) * 32 + lhi * 8;
        bf16x8 a[2], b[3];
#pragma unroll
        for (int m = 0; m < 2; m++)
            a[m] = *reinterpret_cast<bf16x8*>(&A2[1][w * 32 + m * 16 + l15][ka]);
#pragma unroll
        for (int n = 0; n < 3; n++)
            b[n] = *reinterpret_cast<const bf16x8*>(Wcat + (n * 8 + ks) * 512 + lane * 8);
#pragma unroll
        for (int m = 0; m < 2; m++)
#pragma unroll
            for (int n = 0; n < 3; n++)
                acc[m][n] = __builtin_amdgcn_mfma_f32_16x16x32_bf16(a[m], b[n], acc[m][n], 0, 0, 0);
    }
    // epilogue: bias + log_softmax per row (row lives in a 16-lane group)
    float b0 = bias[l15];
    float b1 = bias[16 + l15];
    float b2 = (l15 < 8) ? bias[32 + l15] : 0.f;
#pragma unroll
    for (int m = 0; m < 2; m++) {
#pragma unroll
        for (int j = 0; j < 4; j++) {
            int grow = row0 + w * 32 + m * 16 + lhi * 4 + j;
            float v0 = acc[m][0][j] + b0;
            float v1 = acc[m][1][j] + b1;
            float v2 = (l15 < 8) ? (acc[m][2][j] + b2) : -INFINITY;
            float mx = fmaxf(fmaxf(v0, v1), v2);
#pragma unroll
            for (int off = 1; off < 16; off <<= 1) mx = fmaxf(mx, __shfl_xor(mx, off, 64));
            float s = expf(v0 - mx) + expf(v1 - mx) + ((l15 < 8) ? expf(v2 - mx) : 0.f);
#pragma unroll
            for (int off = 1; off < 16; off <<= 1) s += __shfl_xor(s, off, 64);
            float lg = mx + logf(s);
            if (grow < N_NODES) {
                out[(size_t)grow * DOUT + l15] = v0 - lg;
                out[(size_t)grow * DOUT + 16 + l15] = v1 - lg;
                if (l15 < 8) out[(size_t)grow * DOUT + 32 + l15] = v2 - lg;
            }
        }
    }
}

// ---------------- launch ----------------
extern "C" void kernel_launch(void* const* d_in, const int* in_sizes, int n_in,
                              void* d_out, int out_size, void* d_ws, size_t ws_size,
                              hipStream_t stream) {
    const float* x = (const float*)d_in[0];
    const int* ei = (const int*)d_in[1];
    const float* w1 = (const float*)d_in[2];
    const float* r1 = (const float*)d_in[3];
    const float* b1 = (const float*)d_in[4];
    const float* g1 = (const float*)d_in[5];
    const float* be1 = (const float*)d_in[6];
    const float* w2 = (const float*)d_in[7];
    const float* r2 = (const float*)d_in[8];
    const float* b2 = (const float*)d_in[9];
    const float* g2 = (const float*)d_in[10];
    const float* be2 = (const float*)d_in[11];
    const float* w3 = (const float*)d_in[12];
    const float* r3 = (const float*)d_in[13];
    const float* b3 = (const float*)d_in[14];
    float* out = (float*)d_out;

    const size_t NF = (size_t)N_NODES * DIM;  // 12.8M
    ushort* Xb = (ushort*)d_ws;
    ushort* Ab = Xb + NF;
    ushort* Bb = Ab + NF;
    ushort* Wc1 = Bb + NF;             // 128*256
    ushort* Wc2 = Wc1 + 128 * 256;
    ushort* Wc3 = Wc2 + 128 * 256;     // 48*256
    uint* bucketbuf = (uint*)(Wc3 + 48 * 256);   // NB*BCAP = 2.048M uints
    int* gcnt = (int*)(bucketbuf + (size_t)NB * BCAP);  // NB
    float* statsA = (float*)(gcnt + NB);          // 256 (sum+sumsq)
    float* statsB = statsA + 256;                 // 256
    int* rowstart = (int*)(statsB + 256);         // N+1
    int* csr = rowstart + (N_NODES + 1);          // E
    size_t needed = (size_t)((char*)(csr + N_EDGES) - (char*)d_ws);
    if (ws_size < needed) return;

    const int AGG_BLOCKS = N_NODES / 4;               // 25000
    const int GEMM_BLOCKS = (N_NODES + 127) / 128;    // 782
    const int PREP_BLOCKS = BKT_BLOCKS + 2048 + 304;  // 2752

    // zero gcnt + stats, then fused prep (bucket first + cvt + wcat x3)
    hipMemsetAsync(gcnt, 0, (NB + 512) * sizeof(int), stream);
    k_prep<<<PREP_BLOCKS, 256, 0, stream>>>(x, Xb, w1, r1, Wc1, w2, r2, Wc2, w3, r3, Wc3,
                                            ei, bucketbuf, gcnt);
    k_csr_build<<<NB, 256, 0, stream>>>(ei, bucketbuf, gcnt, rowstart, csr);

    // ---- layer 1 ----
    k_agg_bf<<<AGG_BLOCKS, 256, 0, stream>>>(Xb, rowstart, csr, Ab);
    k_gemm_mfma<<<GEMM_BLOCKS, 256, 0, stream>>>(Ab, Xb, Wc1, b1, Ab, statsA, 1);
    k_bnrelu<<<2048, 256, 0, stream>>>(Ab, statsA, g1, be1);   // Ab := bnrelu(h1)

    // ---- layer 2 ----
    k_agg_bf<<<AGG_BLOCKS, 256, 0, stream>>>(Ab, rowstart, csr, Bb);
    k_gemm_mfma<<<GEMM_BLOCKS, 256, 0, stream>>>(Bb, Ab, Wc2, b2, Bb, statsB, 1);
    k_bnrelu<<<2048, 256, 0, stream>>>(Bb, statsB, g2, be2);   // Bb := bnrelu(h2)

    // ---- layer 3 ----
    k_agg_bf<<<AGG_BLOCKS, 256, 0, stream>>>(Bb, rowstart, csr, Ab);
    k_gemm40_mfma<<<GEMM_BLOCKS, 256, 0, stream>>>(Ab, Bb, Wc3, b3, out);
}

// Round 18
// 359.415 us; speedup vs baseline: 1.0057x; 1.0057x over previous
//
#include <hip/hip_runtime.h>
#include <cstdint>
#include <cstddef>
#include <math.h>

#define N_NODES 100000
#define N_EDGES 1600000
#define DIM 128
#define DOUT 40
#define BN_EPS 1e-5f

// bucketed CSR build
#define NB 500          // buckets
#define NPB 200         // nodes per bucket (500*200 = 100000 exactly)
#define BCAP 4096       // bucket capacity (mean 3200 -> ~16 sigma headroom)
#define BKT_BLOCKS 400
#define EPB (N_EDGES / BKT_BLOCKS)   // 4000

typedef __attribute__((ext_vector_type(8))) short bf16x8;
typedef __attribute__((ext_vector_type(4))) float f32x4;

__device__ __forceinline__ float bf2f(uint u16shifted) {
    union { uint i; float f; } c; c.i = u16shifted; return c.f;
}
__device__ __forceinline__ ushort f2bf(float f) {
    union { float f; uint i; } c; c.f = f;
    uint i = c.i;
    uint lsb = (i >> 16) & 1u;
    i += 0x7FFFu + lsb;
    return (ushort)(i >> 16);
}
__device__ __forceinline__ uint bnpack(uint u, float s0, float h0, float s1, float h1) {
    float lo = fmaxf(bf2f(u << 16) * s0 + h0, 0.f);
    float hi = fmaxf(bf2f(u & 0xFFFF0000u) * s1 + h1, 0.f);
    return (uint)f2bf(lo) | ((uint)f2bf(hi) << 16);
}

// Wcat FRAGMENT layout: for col-fragment fc (=col>>4) and K-step ks (=k>>5),
// fragment base = (fc*8+ks)*512 ushorts; within, lane l holds elems l*8..l*8+7
__device__ __forceinline__ void wcat_body(const float* __restrict__ W,
                                          const float* __restrict__ R,
                                          ushort* __restrict__ out, int NW, int blk) {
    int idx = blk * 256 + threadIdx.x;      // idx over Ncols*256
    int n = idx >> 8, k = idx & 255;
    float v = 0.f;
    if (n < NW) v = (k < 128) ? W[k * NW + n] : R[(k - 128) * NW + n];
    int fc = n >> 4, l15 = n & 15;
    int ks = k >> 5, lhi = (k & 31) >> 3, j = k & 7;
    out[(fc * 8 + ks) * 512 + (lhi * 16 + l15) * 8 + j] = f2bf(v);
}

// ---------------- fused prep: bucket (0..399, int4-vectorized) + cvt + wcat x3 -------------
__global__ __launch_bounds__(256) void k_prep(const float* __restrict__ x,
                                              ushort* __restrict__ Xb,
                                              const float* __restrict__ w1, const float* __restrict__ r1, ushort* __restrict__ Wc1,
                                              const float* __restrict__ w2, const float* __restrict__ r2, ushort* __restrict__ Wc2,
                                              const float* __restrict__ w3, const float* __restrict__ r3, ushort* __restrict__ Wc3,
                                              const int* __restrict__ ei,
                                              uint* __restrict__ bucketbuf,
                                              int* __restrict__ gcnt) {
    int b = blockIdx.x;
    int tid = threadIdx.x;
    if (b < BKT_BLOCKS) {
        // bucket pass: partition edges into dst-buckets; int4 loads = 4 edges/thread/iter
        __shared__ int hist[NB];
        __shared__ int base_[NB];
        for (int i = tid; i < NB; i += 256) hist[i] = 0;
        __syncthreads();
        int e0 = b * EPB, e1 = e0 + EPB;
        for (int e = e0 + tid * 4; e < e1; e += 1024) {
            int4 d4 = *reinterpret_cast<const int4*>(ei + N_EDGES + e);
            atomicAdd(&hist[d4.x / NPB], 1);
            atomicAdd(&hist[d4.y / NPB], 1);
            atomicAdd(&hist[d4.z / NPB], 1);
            atomicAdd(&hist[d4.w / NPB], 1);
        }
        __syncthreads();
        for (int i = tid; i < NB; i += 256) base_[i] = atomicAdd(&gcnt[i], hist[i]);
        __syncthreads();
        for (int i = tid; i < NB; i += 256) hist[i] = 0;
        __syncthreads();
        for (int e = e0 + tid * 4; e < e1; e += 1024) {
            int4 d4 = *reinterpret_cast<const int4*>(ei + N_EDGES + e);
            int4 s4 = *reinterpret_cast<const int4*>(ei + e);
            int bk0 = d4.x / NPB, bk1 = d4.y / NPB, bk2 = d4.z / NPB, bk3 = d4.w / NPB;
            int p0 = base_[bk0] + atomicAdd(&hist[bk0], 1);
            int p1 = base_[bk1] + atomicAdd(&hist[bk1], 1);
            int p2 = base_[bk2] + atomicAdd(&hist[bk2], 1);
            int p3 = base_[bk3] + atomicAdd(&hist[bk3], 1);
            if (p0 < BCAP) bucketbuf[(size_t)bk0 * BCAP + p0] = ((uint)(d4.x - bk0 * NPB) << 17) | (uint)s4.x;
            if (p1 < BCAP) bucketbuf[(size_t)bk1 * BCAP + p1] = ((uint)(d4.y - bk1 * NPB) << 17) | (uint)s4.y;
            if (p2 < BCAP) bucketbuf[(size_t)bk2 * BCAP + p2] = ((uint)(d4.z - bk2 * NPB) << 17) | (uint)s4.z;
            if (p3 < BCAP) bucketbuf[(size_t)bk3 * BCAP + p3] = ((uint)(d4.w - bk3 * NPB) << 17) | (uint)s4.w;
        }
    } else if (b < BKT_BLOCKS + 2048) {
        int n4 = N_NODES * DIM / 4;
        int i = (b - BKT_BLOCKS) * 256 + tid;
        int stride = 2048 * 256;
        for (; i < n4; i += stride) {
            float4 v = reinterpret_cast<const float4*>(x)[i];
            ushort4 o;
            o.x = f2bf(v.x); o.y = f2bf(v.y); o.z = f2bf(v.z); o.w = f2bf(v.w);
            reinterpret_cast<ushort4*>(Xb)[i] = o;
        }
    } else if (b < BKT_BLOCKS + 2048 + 128) {
        wcat_body(w1, r1, Wc1, 128, b - (BKT_BLOCKS + 2048));
    } else if (b < BKT_BLOCKS + 2048 + 256) {
        wcat_body(w2, r2, Wc2, 128, b - (BKT_BLOCKS + 2048 + 128));
    } else {
        wcat_body(w3, r3, Wc3, DOUT, b - (BKT_BLOCKS + 2048 + 256));
    }
}

// ---------------- CSR pass B: per-bucket CSR entirely in LDS (self-computed base) ----------
__global__ __launch_bounds__(256) void k_csr_build(const int* __restrict__ ei,
                                                   const uint* __restrict__ bucketbuf,
                                                   const int* __restrict__ gcnt,
                                                   int* __restrict__ rowstart,
                                                   int* __restrict__ csr) {
    __shared__ int cnts[NPB + 1];
    __shared__ int lcur[NPB];
    __shared__ int csr_l[BCAP];
    __shared__ int baseS;
    int b = blockIdx.x, tid = threadIdx.x;
    int cnt = gcnt[b];
    int lo = b * NPB;
    if (tid == 0) baseS = 0;
    for (int i = tid; i < NPB; i += 256) cnts[i] = 0;
    __syncthreads();
    int part = 0;
    for (int i = tid; i < b; i += 256) part += gcnt[i];
    if (part) atomicAdd(&baseS, part);
    bool fits = (cnt <= BCAP);
    if (fits) {
        for (int i = tid; i < cnt; i += 256)
            atomicAdd(&cnts[bucketbuf[(size_t)b * BCAP + i] >> 17], 1);
    } else {  // overflow fallback (statistically never)
        for (int e = tid; e < N_EDGES; e += 256) {
            int d = ei[N_EDGES + e];
            if (d >= lo && d < lo + NPB) atomicAdd(&cnts[d - lo], 1);
        }
    }
    __syncthreads();
    int base = baseS;
    if (tid == 0) {
        int run = 0;
        for (int i = 0; i < NPB; i++) { int c = cnts[i]; cnts[i] = run; run += c; }
        cnts[NPB] = run;
    }
    __syncthreads();
    for (int i = tid; i < NPB; i += 256) rowstart[lo + i] = base + cnts[i];
    if (b == NB - 1 && tid == 0) rowstart[N_NODES] = N_EDGES;
    for (int i = tid; i < NPB; i += 256) lcur[i] = 0;
    __syncthreads();
    if (fits) {
        for (int i = tid; i < cnt; i += 256) {
            uint p = bucketbuf[(size_t)b * BCAP + i];
            int dl = p >> 17;
            int pos = cnts[dl] + atomicAdd(&lcur[dl], 1);
            csr_l[pos] = (int)(p & 0x1FFFFu);
        }
        __syncthreads();
        for (int i = tid; i < cnt; i += 256) csr[base + i] = csr_l[i];
    } else {
        for (int e = tid; e < N_EDGES; e += 256) {
            int d = ei[N_EDGES + e];
            if (d >= lo && d < lo + NPB) {
                int dl = d - lo;
                int pos = cnts[dl] + atomicAdd(&lcur[dl], 1);
                csr[base + pos] = ei[e];
            }
        }
    }
}

// ---------------- BN+ReLU materialization, in-place, vectorized ----------------
__global__ __launch_bounds__(256) void k_bnrelu(ushort* __restrict__ H,
                                                const float* __restrict__ stats,
                                                const float* __restrict__ g,
                                                const float* __restrict__ be) {
    __shared__ float scS[128], shS[128];
    int tid = threadIdx.x;
    if (tid < 128) {
        float mu = stats[tid] * (1.0f / N_NODES);
        float var = stats[128 + tid] * (1.0f / N_NODES) - mu * mu;
        float sc = g[tid] * rsqrtf(var + BN_EPS);
        scS[tid] = sc;
        shS[tid] = be[tid] - mu * sc;
    }
    __syncthreads();
    uint4* H4 = reinterpret_cast<uint4*>(H);
    const int total = N_NODES * 16;   // uint4 per row = 16
    for (int i = blockIdx.x * 256 + tid; i < total; i += gridDim.x * 256) {
        uint4 u = H4[i];
        int c0 = (i & 15) * 8;
        u.x = bnpack(u.x, scS[c0 + 0], shS[c0 + 0], scS[c0 + 1], shS[c0 + 1]);
        u.y = bnpack(u.y, scS[c0 + 2], shS[c0 + 2], scS[c0 + 3], shS[c0 + 3]);
        u.z = bnpack(u.z, scS[c0 + 4], shS[c0 + 4], scS[c0 + 5], shS[c0 + 5]);
        u.w = bnpack(u.w, scS[c0 + 6], shS[c0 + 6], scS[c0 + 7], shS[c0 + 7]);
        H4[i] = u;
    }
}

// ---------------- mean aggregation, bf16, 4 edges in flight (pure unpack+add) ------
__global__ __launch_bounds__(256) void k_agg_bf(const ushort* __restrict__ cur,
                                                const int* __restrict__ rowstart,
                                                const int* __restrict__ csr,
                                                ushort* __restrict__ out) {
    int wid = (blockIdx.x * blockDim.x + threadIdx.x) >> 6;
    int lane = threadIdx.x & 63;
    if (wid >= N_NODES) return;
    int beg = rowstart[wid];
    int end = rowstart[wid + 1];
    int slot = lane >> 4;   // which edge within a group of 4
    int cg = lane & 15;     // column group: cols cg*8 .. cg*8+7
    const uint4* base = reinterpret_cast<const uint4*>(cur);
    float a0 = 0.f, a1 = 0.f, a2 = 0.f, a3 = 0.f, a4 = 0.f, a5 = 0.f, a6 = 0.f, a7 = 0.f;
#pragma unroll 2
    for (int e = beg + slot; e < end; e += 4) {
        int s = csr[e];
        uint4 u = base[(size_t)s * 16 + cg];
        a0 += bf2f(u.x << 16); a1 += bf2f(u.x & 0xFFFF0000u);
        a2 += bf2f(u.y << 16); a3 += bf2f(u.y & 0xFFFF0000u);
        a4 += bf2f(u.z << 16); a5 += bf2f(u.z & 0xFFFF0000u);
        a6 += bf2f(u.w << 16); a7 += bf2f(u.w & 0xFFFF0000u);
    }
#pragma unroll
    for (int off = 16; off < 64; off <<= 1) {
        a0 += __shfl_xor(a0, off, 64); a1 += __shfl_xor(a1, off, 64);
        a2 += __shfl_xor(a2, off, 64); a3 += __shfl_xor(a3, off, 64);
        a4 += __shfl_xor(a4, off, 64); a5 += __shfl_xor(a5, off, 64);
        a6 += __shfl_xor(a6, off, 64); a7 += __shfl_xor(a7, off, 64);
    }
    if (slot == 0) {
        int deg = end - beg;
        float inv = 1.0f / (float)(deg > 1 ? deg : 1);
        uint4 o;
        o.x = (uint)f2bf(a0 * inv) | ((uint)f2bf(a1 * inv) << 16);
        o.y = (uint)f2bf(a2 * inv) | ((uint)f2bf(a3 * inv) << 16);
        o.z = (uint)f2bf(a4 * inv) | ((uint)f2bf(a5 * inv) << 16);
        o.w = (uint)f2bf(a6 * inv) | ((uint)f2bf(a7 * inv) << 16);
        reinterpret_cast<uint4*>(out)[(size_t)wid * 16 + cg] = o;
    }
}

// ---------------- MFMA GEMM v4: pipelined staging (mean LDS -> self regs in flight) -------
// out[M,128] = mean@W + cur@R + b, fused col-stats.
__global__ __launch_bounds__(256, 2) void k_gemm_mfma(const ushort* __restrict__ Am,
                                                      const ushort* __restrict__ Ac,
                                                      const ushort* __restrict__ Wcat, // frag layout
                                                      const float* __restrict__ bias,
                                                      ushort* __restrict__ out,
                                                      float* __restrict__ stats_out,
                                                      int dostats) {
    __shared__ ushort A2[2][128][136];   // 69.6 KB
    __shared__ float lsum[128], lsumsq[128];
    int tid = threadIdx.x;
    int wid = tid >> 6, lane = tid & 63;
    int wr = wid >> 1, wc = wid & 1;
    int l15 = lane & 15, lhi = lane >> 4;
    int row0 = blockIdx.x * 128;

    if (tid < 128) { lsum[tid] = 0.f; lsumsq[tid] = 0.f; }

    // stage mean half into LDS[0]
#pragma unroll
    for (int i = 0; i < 8; ++i) {
        int idx = i * 256 + tid;
        int row = idx >> 4, q = idx & 15;
        int gr = row0 + row;
        uint4 v = {0, 0, 0, 0};
        if (gr < N_NODES)
            v = *reinterpret_cast<const uint4*>(Am + (size_t)gr * 128 + q * 8);
        *reinterpret_cast<uint4*>(&A2[0][row][q * 8]) = v;
    }
    // issue self-half loads into registers (in flight across the first MFMA phase)
    uint4 sreg[8];
#pragma unroll
    for (int i = 0; i < 8; ++i) {
        int idx = i * 256 + tid;
        int row = idx >> 4, q = idx & 15;
        int gr = row0 + row;
        uint4 v = {0, 0, 0, 0};
        if (gr < N_NODES)
            v = *reinterpret_cast<const uint4*>(Ac + (size_t)gr * 128 + q * 8);
        sreg[i] = v;
    }
    __syncthreads();

    f32x4 acc[4][4];
#pragma unroll
    for (int m = 0; m < 4; m++)
#pragma unroll
        for (int n = 0; n < 4; n++) acc[m][n] = (f32x4){0.f, 0.f, 0.f, 0.f};

    // ks 0..3 on mean half (self loads still in flight)
#pragma unroll
    for (int ks = 0; ks < 4; ++ks) {
        int ka = ks * 32 + lhi * 8;
        bf16x8 a[4], b[4];
#pragma unroll
        for (int m = 0; m < 4; m++)
            a[m] = *reinterpret_cast<bf16x8*>(&A2[0][wr * 64 + m * 16 + l15][ka]);
#pragma unroll
        for (int n = 0; n < 4; n++)
            b[n] = *reinterpret_cast<const bf16x8*>(Wcat + ((wc * 4 + n) * 8 + ks) * 512 + lane * 8);
#pragma unroll
        for (int m = 0; m < 4; m++)
#pragma unroll
            for (int n = 0; n < 4; n++)
                acc[m][n] = __builtin_amdgcn_mfma_f32_16x16x32_bf16(a[m], b[n], acc[m][n], 0, 0, 0);
    }
    // write self half to LDS[1]
#pragma unroll
    for (int i = 0; i < 8; ++i) {
        int idx = i * 256 + tid;
        int row = idx >> 4, q = idx & 15;
        *reinterpret_cast<uint4*>(&A2[1][row][q * 8]) = sreg[i];
    }
    __syncthreads();
    // ks 4..7 on self half
#pragma unroll
    for (int ks = 4; ks < 8; ++ks) {
        int ka = (ks - 4) * 32 + lhi * 8;
        bf16x8 a[4], b[4];
#pragma unroll
        for (int m = 0; m < 4; m++)
            a[m] = *reinterpret_cast<bf16x8*>(&A2[1][wr * 64 + m * 16 + l15][ka]);
#pragma unroll
        for (int n = 0; n < 4; n++)
            b[n] = *reinterpret_cast<const bf16x8*>(Wcat + ((wc * 4 + n) * 8 + ks) * 512 + lane * 8);
#pragma unroll
        for (int m = 0; m < 4; m++)
#pragma unroll
            for (int n = 0; n < 4; n++)
                acc[m][n] = __builtin_amdgcn_mfma_f32_16x16x32_bf16(a[m], b[n], acc[m][n], 0, 0, 0);
    }
    // epilogue: + bias, bf16 store, per-column stats partials
    float ps[4] = {0.f, 0.f, 0.f, 0.f}, ps2[4] = {0.f, 0.f, 0.f, 0.f};
#pragma unroll
    for (int m = 0; m < 4; m++) {
        int rbase = row0 + wr * 64 + m * 16 + lhi * 4;
#pragma unroll
        for (int n = 0; n < 4; n++) {
            int col = wc * 64 + n * 16 + l15;
            float bv = bias[col];
#pragma unroll
            for (int j = 0; j < 4; j++) {
                int gr = rbase + j;
                if (gr < N_NODES) {
                    float v = acc[m][n][j] + bv;
                    out[(size_t)gr * 128 + col] = f2bf(v);
                    ps[n] += v;
                    ps2[n] += v * v;
                }
            }
        }
    }
    if (dostats) {
#pragma unroll
        for (int n = 0; n < 4; n++) {
            ps[n] += __shfl_xor(ps[n], 16, 64);
            ps2[n] += __shfl_xor(ps2[n], 16, 64);
            ps[n] += __shfl_xor(ps[n], 32, 64);
            ps2[n] += __shfl_xor(ps2[n], 32, 64);
        }
        if (lhi == 0) {
#pragma unroll
            for (int n = 0; n < 4; n++) {
                int col = wc * 64 + n * 16 + l15;
                atomicAdd(&lsum[col], ps[n]);
                atomicAdd(&lsumsq[col], ps2[n]);
            }
        }
        __syncthreads();
        if (tid < 128) {
            atomicAdd(&stats_out[tid], lsum[tid]);
            atomicAdd(&stats_out[128 + tid], lsumsq[tid]);
        }
    }
}

// ---------------- layer-3 GEMM v4: pipelined staging + frag B + bias + log_softmax --------
__global__ __launch_bounds__(256, 2) void k_gemm40_mfma(const ushort* __restrict__ Am,
                                                        const ushort* __restrict__ Ac,
                                                        const ushort* __restrict__ Wcat, // frag layout [3 fc][8 ks][512]
                                                        const float* __restrict__ bias,  // [40]
                                                        float* __restrict__ out) {
    __shared__ ushort A2[2][128][136];
    int tid = threadIdx.x;
    int w = tid >> 6, lane = tid & 63;
    int l15 = lane & 15, lhi = lane >> 4;
    int row0 = blockIdx.x * 128;

    // stage mean half
#pragma unroll
    for (int i = 0; i < 8; ++i) {
        int idx = i * 256 + tid;
        int row = idx >> 4, q = idx & 15;
        int gr = row0 + row;
        uint4 v = {0, 0, 0, 0};
        if (gr < N_NODES)
            v = *reinterpret_cast<const uint4*>(Am + (size_t)gr * 128 + q * 8);
        *reinterpret_cast<uint4*>(&A2[0][row][q * 8]) = v;
    }
    uint4 sreg[8];
#pragma unroll
    for (int i = 0; i < 8; ++i) {
        int idx = i * 256 + tid;
        int row = idx >> 4, q = idx & 15;
        int gr = row0 + row;
        uint4 v = {0, 0, 0, 0};
        if (gr < N_NODES)
            v = *reinterpret_cast<const uint4*>(Ac + (size_t)gr * 128 + q * 8);
        sreg[i] = v;
    }
    __syncthreads();

    f32x4 acc[2][3];
#pragma unroll
    for (int m = 0; m < 2; m++)
#pragma unroll
        for (int n = 0; n < 3; n++) acc[m][n] = (f32x4){0.f, 0.f, 0.f, 0.f};

#pragma unroll
    for (int ks = 0; ks < 4; ++ks) {
        int ka = ks * 32 + lhi * 8;
        bf16x8 a[2], b[3];
#pragma unroll
        for (int m = 0; m < 2; m++)
            a[m] = *reinterpret_cast<bf16x8*>(&A2[0][w * 32 + m * 16 + l15][ka]);
#pragma unroll
        for (int n = 0; n < 3; n++)
            b[n] = *reinterpret_cast<const bf16x8*>(Wcat + (n * 8 + ks) * 512 + lane * 8);
#pragma unroll
        for (int m = 0; m < 2; m++)
#pragma unroll
            for (int n = 0; n < 3; n++)
                acc[m][n] = __builtin_amdgcn_mfma_f32_16x16x32_bf16(a[m], b[n], acc[m][n], 0, 0, 0);
    }
#pragma unroll
    for (int i = 0; i < 8; ++i) {
        int idx = i * 256 + tid;
        int row = idx >> 4, q = idx & 15;
        *reinterpret_cast<uint4*>(&A2[1][row][q * 8]) = sreg[i];
    }
    __syncthreads();
#pragma unroll
    for (int ks = 4; ks < 8; ++ks) {
        int ka = (ks - 4) * 32 + lhi * 8;
        bf16x8 a[2], b[3];
#pragma unroll
        for (int m = 0; m < 2; m++)
            a[m] = *reinterpret_cast<bf16x8*>(&A2[1][w * 32 + m * 16 + l15][ka]);
#pragma unroll
        for (int n = 0; n < 3; n++)
            b[n] = *reinterpret_cast<const bf16x8*>(Wcat + (n * 8 + ks) * 512 + lane * 8);
#pragma unroll
        for (int m = 0; m < 2; m++)
#pragma unroll
            for (int n = 0; n < 3; n++)
                acc[m][n] = __builtin_amdgcn_mfma_f32_16x16x32_bf16(a[m], b[n], acc[m][n], 0, 0, 0);
    }
    // epilogue: bias + log_softmax per row (row lives in a 16-lane group)
    float b0 = bias[l15];
    float b1 = bias[16 + l15];
    float b2 = (l15 < 8) ? bias[32 + l15] : 0.f;
#pragma unroll
    for (int m = 0; m < 2; m++) {
#pragma unroll
        for (int j = 0; j < 4; j++) {
            int grow = row0 + w * 32 + m * 16 + lhi * 4 + j;
            float v0 = acc[m][0][j] + b0;
            float v1 = acc[m][1][j] + b1;
            float v2 = (l15 < 8) ? (acc[m][2][j] + b2) : -INFINITY;
            float mx = fmaxf(fmaxf(v0, v1), v2);
#pragma unroll
            for (int off = 1; off < 16; off <<= 1) mx = fmaxf(mx, __shfl_xor(mx, off, 64));
            float s = expf(v0 - mx) + expf(v1 - mx) + ((l15 < 8) ? expf(v2 - mx) : 0.f);
#pragma unroll
            for (int off = 1; off < 16; off <<= 1) s += __shfl_xor(s, off, 64);
            float lg = mx + logf(s);
            if (grow < N_NODES) {
                out[(size_t)grow * DOUT + l15] = v0 - lg;
                out[(size_t)grow * DOUT + 16 + l15] = v1 - lg;
                if (l15 < 8) out[(size_t)grow * DOUT + 32 + l15] = v2 - lg;
            }
        }
    }
}

// ---------------- launch ----------------
extern "C" void kernel_launch(void* const* d_in, const int* in_sizes, int n_in,
                              void* d_out, int out_size, void* d_ws, size_t ws_size,
                              hipStream_t stream) {
    const float* x = (const float*)d_in[0];
    const int* ei = (const int*)d_in[1];
    const float* w1 = (const float*)d_in[2];
    const float* r1 = (const float*)d_in[3];
    const float* b1 = (const float*)d_in[4];
    const float* g1 = (const float*)d_in[5];
    const float* be1 = (const float*)d_in[6];
    const float* w2 = (const float*)d_in[7];
    const float* r2 = (const float*)d_in[8];
    const float* b2 = (const float*)d_in[9];
    const float* g2 = (const float*)d_in[10];
    const float* be2 = (const float*)d_in[11];
    const float* w3 = (const float*)d_in[12];
    const float* r3 = (const float*)d_in[13];
    const float* b3 = (const float*)d_in[14];
    float* out = (float*)d_out;

    const size_t NF = (size_t)N_NODES * DIM;  // 12.8M
    ushort* Xb = (ushort*)d_ws;
    ushort* Ab = Xb + NF;
    ushort* Bb = Ab + NF;
    ushort* Wc1 = Bb + NF;             // 128*256
    ushort* Wc2 = Wc1 + 128 * 256;
    ushort* Wc3 = Wc2 + 128 * 256;     // 48*256
    uint* bucketbuf = (uint*)(Wc3 + 48 * 256);   // NB*BCAP = 2.048M uints
    int* gcnt = (int*)(bucketbuf + (size_t)NB * BCAP);  // NB
    float* statsA = (float*)(gcnt + NB);          // 256 (sum+sumsq)
    float* statsB = statsA + 256;                 // 256
    int* rowstart = (int*)(statsB + 256);         // N+1
    int* csr = rowstart + (N_NODES + 1);          // E
    size_t needed = (size_t)((char*)(csr + N_EDGES) - (char*)d_ws);
    if (ws_size < needed) return;

    const int AGG_BLOCKS = N_NODES / 4;               // 25000
    const int GEMM_BLOCKS = (N_NODES + 127) / 128;    // 782
    const int PREP_BLOCKS = BKT_BLOCKS + 2048 + 304;  // 2752

    // zero gcnt + stats, then fused prep (bucket first + cvt + wcat x3)
    hipMemsetAsync(gcnt, 0, (NB + 512) * sizeof(int), stream);
    k_prep<<<PREP_BLOCKS, 256, 0, stream>>>(x, Xb, w1, r1, Wc1, w2, r2, Wc2, w3, r3, Wc3,
                                            ei, bucketbuf, gcnt);
    k_csr_build<<<NB, 256, 0, stream>>>(ei, bucketbuf, gcnt, rowstart, csr);

    // ---- layer 1 ----
    k_agg_bf<<<AGG_BLOCKS, 256, 0, stream>>>(Xb, rowstart, csr, Ab);
    k_gemm_mfma<<<GEMM_BLOCKS, 256, 0, stream>>>(Ab, Xb, Wc1, b1, Ab, statsA, 1);
    k_bnrelu<<<2048, 256, 0, stream>>>(Ab, statsA, g1, be1);   // Ab := bnrelu(h1)

    // ---- layer 2 ----
    k_agg_bf<<<AGG_BLOCKS, 256, 0, stream>>>(Ab, rowstart, csr, Bb);
    k_gemm_mfma<<<GEMM_BLOCKS, 256, 0, stream>>>(Bb, Ab, Wc2, b2, Bb, statsB, 1);
    k_bnrelu<<<2048, 256, 0, stream>>>(Bb, statsB, g2, be2);   // Bb := bnrelu(h2)

    // ---- layer 3 ----
    k_agg_bf<<<AGG_BLOCKS, 256, 0, stream>>>(Bb, rowstart, csr, Ab);
    k_gemm40_mfma<<<GEMM_BLOCKS, 256, 0, stream>>>(Ab, Bb, Wc3, b3, out);
}